// Round 6
// baseline (756.413 us; speedup 1.0000x reference)
//
#include <hip/hip_runtime.h>
#include <hip/hip_bf16.h>
#include <hip/hip_fp16.h>
#include <math.h>

#define NN 25000
#define EE 400000
#define BB 64
#define FF 32
#define EDD 8
#define HH 4
#define CC 32
#define HCC 128
#define LL 4
#define LINN 128

#define RSQRT_C 0.17677669529663687f  // 1/sqrt(32)
#define NREP 16                        // bnpart replicas
#define LSTATS_WORDS (NREP * 64 + BB * 32 * 2)   // bnpart + gmax + gsum

// ---------------- CSR build ----------------

__global__ void deg_kernel(const int* __restrict__ dst, int* __restrict__ deg) {
    int i = blockIdx.x * blockDim.x + threadIdx.x;
    if (i < EE) atomicAdd(&deg[dst[i]], 1);
}

// batch_index is sorted: counts via binary search, zero atomics
__global__ void counts_kernel(const int* __restrict__ bidx, float* __restrict__ counts) {
    int b = threadIdx.x;
    if (b < BB) {
        int lo = 0, hi = NN;
        while (lo < hi) { int mid = (lo + hi) >> 1; if (bidx[mid] < b) lo = mid + 1; else hi = mid; }
        int s = lo;
        lo = 0; hi = NN;
        while (lo < hi) { int mid = (lo + hi) >> 1; if (bidx[mid] < b + 1) lo = mid + 1; else hi = mid; }
        counts[b] = (float)(lo - s);
    }
}

// inclusive scan within 256-blocks; writes to rowp[i+1], block totals to blks
__global__ void scan1_kernel(const int* __restrict__ deg, int* __restrict__ rowp, int* __restrict__ blks) {
    __shared__ int s[256];
    int i = blockIdx.x * 256 + threadIdx.x;
    int v = (i < NN) ? deg[i] : 0;
    s[threadIdx.x] = v;
    __syncthreads();
    for (int off = 1; off < 256; off <<= 1) {
        int t = (threadIdx.x >= off) ? s[threadIdx.x - off] : 0;
        __syncthreads();
        s[threadIdx.x] += t;
        __syncthreads();
    }
    if (i < NN) rowp[i + 1] = s[threadIdx.x];
    if (threadIdx.x == 255) blks[blockIdx.x] = s[255];
}

// parallel exclusive scan of block totals (nb <= 128)
__global__ void scan2_kernel(int* __restrict__ blks, int nb) {
    __shared__ int s[128];
    int t = threadIdx.x;
    int v = (t < nb) ? blks[t] : 0;
    s[t] = v;
    __syncthreads();
    for (int off = 1; off < 128; off <<= 1) {
        int u = (t >= off) ? s[t - off] : 0;
        __syncthreads();
        s[t] += u;
        __syncthreads();
    }
    if (t < nb) blks[t] = s[t] - v;  // exclusive
}

__global__ void scan3_kernel(int* __restrict__ rowp, const int* __restrict__ blks) {
    int i = blockIdx.x * 256 + threadIdx.x;
    if (i < NN) rowp[i + 1] += blks[blockIdx.x];
    if (i == 0) rowp[0] = 0;
}

__global__ void copycur_kernel(const int* __restrict__ rowp, int* __restrict__ cur) {
    int i = blockIdx.x * 256 + threadIdx.x;
    if (i < NN) cur[i] = rowp[i];
}

__global__ void fill_kernel(const int* __restrict__ dst, int* __restrict__ cur, int* __restrict__ eid) {
    int i = blockIdx.x * blockDim.x + threadIdx.x;
    if (i < EE) {
        int pos = atomicAdd(&cur[dst[i]], 1);
        eid[pos] = i;
    }
}

// deterministic order: insertion-sort each node's edge list by edge id
__global__ void sortseg_kernel(const int* __restrict__ rowp, int* __restrict__ eid) {
    int n = blockIdx.x * 256 + threadIdx.x;
    if (n >= NN) return;
    int b = rowp[n], e = rowp[n + 1];
    for (int i = b + 1; i < e; ++i) {
        int key = eid[i];
        int j = i - 1;
        while (j >= b && eid[j] > key) { eid[j + 1] = eid[j]; --j; }
        eid[j + 1] = key;
    }
}

// gather src + edge-attr into CSR order (once per call, reused 4 layers)
__global__ void csr_gather_kernel(const int* __restrict__ csre, const int* __restrict__ srcA,
                                  const float* __restrict__ eattr,
                                  int* __restrict__ csrsrc, float4* __restrict__ ecsr) {
    int j = blockIdx.x * blockDim.x + threadIdx.x;
    if (j < EE) {
        int e = csre[j];
        csrsrc[j] = srcA[e];
        const float4* s = (const float4*)(eattr + (size_t)e * 8);
        ecsr[(size_t)j * 2] = s[0];
        ecsr[(size_t)j * 2 + 1] = s[1];
    }
}

// ---------------- per-layer: q,k,v,skip projections ----------------
// wave 0: q, wave 1: k, wave 2: v, wave 3: skip. lane owns channels 2l, 2l+1.
// k,v stored as fp16 pairs interleaved: uint2 slot {k0k1, v0v1} per (node,lane).
// block 0 also zeroes the per-layer stats region (bnpart/gmax/gsum).
__global__ __launch_bounds__(256) void qkvs_kernel(
    const float* __restrict__ hin,
    const float* __restrict__ Wq, const float* __restrict__ bq,
    const float* __restrict__ Wk, const float* __restrict__ bk,
    const float* __restrict__ Wv, const float* __restrict__ bv,
    const float* __restrict__ Ws, const float* __restrict__ bs,
    float2* __restrict__ qo, __half2* __restrict__ kvo,
    float2* __restrict__ so, float* __restrict__ lstats)
{
    if (blockIdx.x == 0) {
        for (int i = threadIdx.x; i < LSTATS_WORDS; i += 256) lstats[i] = 0.0f;
    }
    __shared__ float xs[32][32];
    int lane = threadIdx.x & 63;
    int sel = threadIdx.x >> 6;
    const float* W = (sel == 0) ? Wq : (sel == 1) ? Wk : (sel == 2) ? Wv : Ws;
    const float* bias = (sel == 0) ? bq : (sel == 1) ? bk : (sel == 2) ? bv : bs;
    float w0[32], w1[32];
#pragma unroll
    for (int f = 0; f < 32; ++f) {
        float2 t = *(const float2*)&W[f * 128 + 2 * lane];
        w0[f] = t.x; w1[f] = t.y;
    }
    float2 bvv = *(const float2*)&bias[2 * lane];

    for (int chunk = blockIdx.x * 32; chunk < NN; chunk += gridDim.x * 32) {
        __syncthreads();
        for (int i = threadIdx.x; i < 1024; i += 256) {
            int nn = chunk + (i >> 5);
            xs[i >> 5][i & 31] = (nn < NN) ? hin[nn * 32 + (i & 31)] : 0.0f;
        }
        __syncthreads();
        int nmax = NN - chunk; if (nmax > 32) nmax = 32;
        for (int nl = 0; nl < nmax; ++nl) {
            float a0 = bvv.x, a1 = bvv.y;
#pragma unroll
            for (int f = 0; f < 32; ++f) {
                float xv = xs[nl][f];
                a0 += xv * w0[f];
                a1 += xv * w1[f];
            }
            size_t node = (size_t)(chunk + nl);
            if (sel == 0)      qo[node * 64 + lane] = make_float2(a0, a1);
            else if (sel == 1) kvo[node * 128 + 2 * lane]     = __float22half2_rn(make_float2(a0, a1));
            else if (sel == 2) kvo[node * 128 + 2 * lane + 1] = __float22half2_rn(make_float2(a0, a1));
            else               so[node * 64 + lane] = make_float2(a0, a1);
        }
    }
}

// ---------------- fused attention + beta gate + Wlin + ELU + BN partials ----------------
// 4 waves/block, 1 dst node per wave. lane owns channels 2*lane, 2*lane+1 (same head).
// Direct exp-sum softmax; kv gather prefetched 2 edges ahead (src 4 ahead).
__global__ __launch_bounds__(256) void attn_kernel(
    const float2* __restrict__ qb, const uint2* __restrict__ kvb,
    const float2* __restrict__ skb,
    const float4* __restrict__ eb4,       // ecsr (2 float4/slot)
    const int* __restrict__ srcArr,       // csrsrc[j]
    const int* __restrict__ rowp,
    const float* __restrict__ WeL, const float* __restrict__ beL,
    const float* __restrict__ WbL,
    const float* __restrict__ WlinL, const float* __restrict__ blinL,
    float* __restrict__ hlin, float* __restrict__ bnpart)
{
    __shared__ float shc[4 * 128];
    __shared__ float sbn[64];

    int tid = threadIdx.x;
    if (tid < 64) sbn[tid] = 0.0f;
    __syncthreads();

    int w = tid >> 6;
    int lane = tid & 63;
    int n = blockIdx.x * 4 + w;

    if (n < NN) {
        float w0[8], w1[8];
#pragma unroll
        for (int d = 0; d < 8; ++d) {
            float2 t = *(const float2*)&WeL[d * 128 + 2 * lane];
            w0[d] = t.x; w1[d] = t.y;
        }
        float2 be2 = *(const float2*)&beL[2 * lane];
        float2 wbo = *(const float2*)&WbL[2 * lane];
        float2 wbs = *(const float2*)&WbL[128 + 2 * lane];
        float2 wbd = *(const float2*)&WbL[256 + 2 * lane];

        float2 q2 = qb[(size_t)n * 64 + lane];
        q2.x *= RSQRT_C; q2.y *= RSQRT_C;          // fold 1/sqrt(C) into q
        float2 sk = skb[(size_t)n * 64 + lane];

        int beg = rowp[n], end = rowp[n + 1];
        int cnt = end - beg;
        int last = end - 1;

        float s = 0.0f, a0 = 0.0f, a1 = 0.0f;

        // pipeline state: kvA = data edge j, kvB = data edge j+1 (in flight),
        // eaA = data edge j, snC/snD = src for edges j+2, j+3
        uint2 kvA = make_uint2(0u, 0u), kvB = kvA;
        float4 eaA0 = make_float4(0.f, 0.f, 0.f, 0.f), eaA1 = eaA0;
        int snC = 0, snD = 0;

        if (cnt > 0) {
            int j1 = (beg + 1 < end) ? beg + 1 : last;
            int j2 = (beg + 2 < end) ? beg + 2 : last;
            int j3 = (beg + 3 < end) ? beg + 3 : last;
            int snA = srcArr[beg];
            int snB = srcArr[j1];
            snC = srcArr[j2];
            snD = srcArr[j3];
            kvA  = kvb[(size_t)snA * 64 + lane];
            kvB  = kvb[(size_t)snB * 64 + lane];
            eaA0 = eb4[(size_t)beg * 2];
            eaA1 = eb4[(size_t)beg * 2 + 1];
        }

        for (int j = beg; j < end; ++j) {
            // issue loads: kv for edge j+2, ea for edge j+1, src for edge j+4
            uint2 kvC = kvb[(size_t)snC * 64 + lane];
            int jn = (j + 1 < end) ? j + 1 : last;
            float4 eaB0 = eb4[(size_t)jn * 2];
            float4 eaB1 = eb4[(size_t)jn * 2 + 1];
            int j4 = (j + 4 < end) ? j + 4 : last;
            int snE = srcArr[j4];

            // compute with current edge (A)
            float e0 = be2.x, e1 = be2.y;
            e0 += eaA0.x * w0[0] + eaA0.y * w0[1] + eaA0.z * w0[2] + eaA0.w * w0[3]
                + eaA1.x * w0[4] + eaA1.y * w0[5] + eaA1.z * w0[6] + eaA1.w * w0[7];
            e1 += eaA0.x * w1[0] + eaA0.y * w1[1] + eaA0.z * w1[2] + eaA0.w * w1[3]
                + eaA1.x * w1[4] + eaA1.y * w1[5] + eaA1.z * w1[6] + eaA1.w * w1[7];
            float2 kf = __half22float2(*(const __half2*)&kvA.x);
            float2 vf = __half22float2(*(const __half2*)&kvA.y);
            float p = q2.x * (kf.x + e0) + q2.y * (kf.y + e1);
#pragma unroll
            for (int off = 1; off <= 8; off <<= 1) p += __shfl_xor(p, off);
            float wg = __expf(p);                 // |p| small by construction: no overflow
            s  += wg;
            a0 = fmaf(wg, vf.x + e0, a0);
            a1 = fmaf(wg, vf.y + e1, a1);

            // rotate pipeline
            kvA = kvB; kvB = kvC;
            eaA0 = eaB0; eaA1 = eaB1;
            snC = snD; snD = snE;
        }

        float rs = (cnt > 0) ? (1.0f / s) : 0.0f;
        float out0 = a0 * rs;
        float out1 = a1 * rs;

        float t = out0 * wbo.x + sk.x * wbs.x + (out0 - sk.x) * wbd.x
                + out1 * wbo.y + sk.y * wbs.y + (out1 - sk.y) * wbd.y;
#pragma unroll
        for (int off = 1; off <= 32; off <<= 1) t += __shfl_xor(t, off);
        float beta = 1.0f / (1.0f + __expf(-t));
        float hc0 = beta * sk.x + (1.0f - beta) * out0;
        float hc1 = beta * sk.y + (1.0f - beta) * out1;
        shc[w * 128 + 2 * lane]     = hc0;
        shc[w * 128 + 2 * lane + 1] = hc1;
        // same-wave LDS RAW: no barrier needed
        int cc = lane & 31;
        int half = lane >> 5;
        float acc = 0.0f;
#pragma unroll 8
        for (int i = 0; i < 64; ++i) {
            int ch = half * 64 + i;
            acc += shc[w * 128 + ch] * WlinL[ch * 32 + cc];
        }
        acc += __shfl_xor(acc, 32);
        if (lane < 32) {
            float hv = acc + blinL[lane];
            hv = (hv > 0.0f) ? hv : expm1f(hv);
            hlin[n * 32 + lane] = hv;
            atomicAdd(&sbn[lane], hv);
            atomicAdd(&sbn[32 + lane], hv * hv);
        }
    }
    __syncthreads();
    if (tid < 64) atomicAdd(&bnpart[(blockIdx.x & (NREP - 1)) * 64 + tid], sbn[tid]);
}

// ---------------- normalize (BN finalize inline) + pooling atomics ----------------
__device__ __forceinline__ unsigned fmap_u(float x) {
    unsigned u = __float_as_uint(x);
    return (u & 0x80000000u) ? ~u : (u | 0x80000000u);
}
__device__ __forceinline__ float funmap_u(unsigned u) {
    unsigned b = (u & 0x80000000u) ? (u & 0x7fffffffu) : ~u;
    return __uint_as_float(b);
}

__global__ void norm_pool_kernel(const float* __restrict__ hl, const float* __restrict__ bnpart,
                                 const float* __restrict__ gamma, const float* __restrict__ bnbeta,
                                 const int* __restrict__ bidx, float* __restrict__ hc,
                                 unsigned* __restrict__ gmax, float* __restrict__ gsum,
                                 int doPool, int doWrite) {
    int i0 = blockIdx.x * blockDim.x + threadIdx.x;
    int stride = gridDim.x * blockDim.x;   // multiple of 32 -> c fixed per thread
    int c = i0 & 31;
    float sm = 0.0f, sq = 0.0f;
#pragma unroll
    for (int r = 0; r < NREP; ++r) { sm += bnpart[r * 64 + c]; sq += bnpart[r * 64 + 32 + c]; }
    float mean = sm * (1.0f / NN);
    float var = sq * (1.0f / NN) - mean * mean;
    float scale = gamma[c] * rsqrtf(var + 1e-5f);
    float shift = bnbeta[c] - mean * scale;
    const int tot = NN * 32;
    for (int i = i0; i < tot; i += stride) {
        int n = i >> 5;
        float val = hl[i] * scale + shift;
        if (doWrite) hc[i] = val;
        if (doPool) {
            int b = bidx[n];
            atomicMax(&gmax[b * 32 + c], fmap_u(val));
            atomicAdd(&gsum[b * 32 + c], val);
        }
    }
}

__global__ void pool_accum_kernel(const unsigned* __restrict__ gmax, const float* __restrict__ gsum,
                                  const float* __restrict__ counts, float* __restrict__ rep) {
    int i = blockIdx.x * blockDim.x + threadIdx.x;
    if (i < BB * 32) {
        int b = i >> 5, c = i & 31;
        rep[b * 64 + c] += funmap_u(gmax[i]);
        rep[b * 64 + 32 + c] += gsum[i] / counts[b];
    }
}

// ---------------- readout MLP: one block per graph ----------------
__device__ __forceinline__ float eluf(float x) { return x > 0.0f ? x : expm1f(x); }

__global__ __launch_bounds__(128) void readout_kernel(
    const float* __restrict__ rep,
    const float* __restrict__ W1, const float* __restrict__ b1,
    const float* __restrict__ W2, const float* __restrict__ b2,
    const float* __restrict__ W3, const float* __restrict__ b3,
    float* __restrict__ out)
{
    __shared__ float sr[64];
    __shared__ float sz1[128];
    __shared__ float sz2[64];
    int g = blockIdx.x;
    int t = threadIdx.x;
    if (t < 64) sr[t] = rep[g * 64 + t];
    __syncthreads();
    float acc = b1[t];
#pragma unroll 8
    for (int i = 0; i < 64; ++i) acc += sr[i] * W1[i * 128 + t];
    sz1[t] = eluf(acc);
    __syncthreads();
    if (t < 64) {
        float a2 = b2[t];
#pragma unroll 8
        for (int i = 0; i < 128; ++i) a2 += sz1[i] * W2[i * 64 + t];
        sz2[t] = eluf(a2);
    }
    __syncthreads();
    if (t < 64) {
        float p = sz2[t] * W3[t];
#pragma unroll
        for (int off = 1; off <= 32; off <<= 1) p += __shfl_xor(p, off);
        if (t == 0) out[g] = p + b3[0];
    }
}

// ---------------- host ----------------

extern "C" void kernel_launch(void* const* d_in, const int* in_sizes, int n_in,
                              void* d_out, int out_size, void* d_ws, size_t ws_size,
                              hipStream_t stream) {
    const float* x      = (const float*)d_in[0];
    const float* eattr  = (const float*)d_in[1];
    const int*   eidx   = (const int*)d_in[2];
    const int*   bidx   = (const int*)d_in[3];
    const float* Wq     = (const float*)d_in[4];
    const float* bq     = (const float*)d_in[5];
    const float* Wk     = (const float*)d_in[6];
    const float* bk     = (const float*)d_in[7];
    const float* Wv     = (const float*)d_in[8];
    const float* bv     = (const float*)d_in[9];
    const float* We     = (const float*)d_in[10];
    const float* be     = (const float*)d_in[11];
    const float* Wskip  = (const float*)d_in[12];
    const float* bskip  = (const float*)d_in[13];
    const float* Wbeta  = (const float*)d_in[14];
    const float* Wlin   = (const float*)d_in[15];
    const float* blin   = (const float*)d_in[16];
    const float* bng    = (const float*)d_in[17];
    const float* bnb    = (const float*)d_in[18];
    const float* W1     = (const float*)d_in[19];
    const float* b1     = (const float*)d_in[20];
    const float* W2     = (const float*)d_in[21];
    const float* b2     = (const float*)d_in[22];
    const float* W3     = (const float*)d_in[23];
    const float* b3     = (const float*)d_in[24];
    float* out = (float*)d_out;

    char* ws = (char*)d_ws;
    size_t off = 0;
    auto alloc = [&](size_t bytes) -> char* {
        char* p = ws + off;
        off = (off + bytes + 255) & ~(size_t)255;
        return p;
    };
    int*    rowp   = (int*)alloc((NN + 1) * 4);
    int*    deg    = (int*)alloc(NN * 4);
    int*    cur    = (int*)alloc(NN * 4);
    int*    csre   = (int*)alloc(EE * 4);
    int*    blks   = (int*)alloc(128 * 4);
    float*  counts = (float*)alloc(BB * 4 + BB * 64 * 4);   // counts + rep contiguous
    float*  rep    = counts + BB;
    float2* qB     = (float2*)alloc((size_t)NN * 64 * 8);
    __half2* kvB   = (__half2*)alloc((size_t)NN * 128 * 4);
    float2* skB    = (float2*)alloc((size_t)NN * 64 * 8);
    float*  hlin   = (float*)alloc((size_t)NN * 32 * 4);
    float*  hcur   = (float*)alloc((size_t)NN * 32 * 4);
    float*  lstats = (float*)alloc(LSTATS_WORDS * 4);       // bnpart + gmax + gsum
    float*    bnpart = lstats;
    unsigned* gmax   = (unsigned*)(lstats + NREP * 64);
    float*    gsum   = lstats + NREP * 64 + BB * 32;

    int*    csrsrc = (int*)alloc(EE * 4);
    float4* ecsr   = (float4*)alloc((size_t)EE * 32);

    const int* srcA = eidx;
    const int* dstA = eidx + EE;

    // --- graph prep (once per call) ---
    (void)hipMemsetAsync(deg, 0, NN * 4, stream);
    (void)hipMemsetAsync(rep, 0, BB * 64 * 4, stream);

    deg_kernel<<<(EE + 255) / 256, 256, 0, stream>>>(dstA, deg);
    counts_kernel<<<1, 64, 0, stream>>>(bidx, counts);
    scan1_kernel<<<98, 256, 0, stream>>>(deg, rowp, blks);
    scan2_kernel<<<1, 128, 0, stream>>>(blks, 98);
    scan3_kernel<<<98, 256, 0, stream>>>(rowp, blks);
    copycur_kernel<<<98, 256, 0, stream>>>(rowp, cur);
    fill_kernel<<<(EE + 255) / 256, 256, 0, stream>>>(dstA, cur, csre);
    sortseg_kernel<<<98, 256, 0, stream>>>(rowp, csre);
    csr_gather_kernel<<<(EE + 255) / 256, 256, 0, stream>>>(csre, srcA, eattr, csrsrc, ecsr);

    const float* hin = x;
    for (int l = 0; l < LL; ++l) {
        qkvs_kernel<<<782, 256, 0, stream>>>(
            hin,
            Wq + l * FF * HCC, bq + l * HCC,
            Wk + l * FF * HCC, bk + l * HCC,
            Wv + l * FF * HCC, bv + l * HCC,
            Wskip + l * FF * HCC, bskip + l * HCC,
            qB, kvB, skB, lstats);

        attn_kernel<<<(NN + 3) / 4, 256, 0, stream>>>(
            qB, (const uint2*)kvB, skB, ecsr, csrsrc, rowp,
            We + l * EDD * HCC, be + l * HCC,
            Wbeta + l * 3 * HCC,
            Wlin + l * HCC * FF, blin + l * FF,
            hlin, bnpart);

        norm_pool_kernel<<<800, 256, 0, stream>>>(hlin, bnpart, bng + l * FF, bnb + l * FF,
                                                  bidx, hcur, gmax, gsum,
                                                  (l > 0) ? 1 : 0, (l < LL - 1) ? 1 : 0);

        if (l > 0) {
            pool_accum_kernel<<<8, 256, 0, stream>>>(gmax, gsum, counts, rep);
        }
        hin = hcur;
    }

    readout_kernel<<<64, 128, 0, stream>>>(rep, W1, b1, W2, b2, W3, b3, out);
}

// Round 7
// 721.304 us; speedup vs baseline: 1.0487x; 1.0487x over previous
//
#include <hip/hip_runtime.h>
#include <hip/hip_bf16.h>
#include <hip/hip_fp16.h>
#include <math.h>

#define NN 25000
#define EE 400000
#define BB 64
#define FF 32
#define EDD 8
#define HH 4
#define CC 32
#define HCC 128
#define LL 4
#define LINN 128

#define RSQRT_C 0.17677669529663687f  // 1/sqrt(32)
#define NREP 16                        // bnpart replicas
#define LSTATS_WORDS (NREP * 64 + BB * 32 * 2)   // bnpart + gmax + gsum

// ---------------- CSR build ----------------

__global__ void deg_kernel(const int* __restrict__ dst, int* __restrict__ deg) {
    int i = blockIdx.x * blockDim.x + threadIdx.x;
    if (i < EE) atomicAdd(&deg[dst[i]], 1);
}

// batch_index is sorted: counts via binary search, zero atomics
__global__ void counts_kernel(const int* __restrict__ bidx, float* __restrict__ counts) {
    int b = threadIdx.x;
    if (b < BB) {
        int lo = 0, hi = NN;
        while (lo < hi) { int mid = (lo + hi) >> 1; if (bidx[mid] < b) lo = mid + 1; else hi = mid; }
        int s = lo;
        lo = 0; hi = NN;
        while (lo < hi) { int mid = (lo + hi) >> 1; if (bidx[mid] < b + 1) lo = mid + 1; else hi = mid; }
        counts[b] = (float)(lo - s);
    }
}

// inclusive scan within 256-blocks; writes to rowp[i+1], block totals to blks
__global__ void scan1_kernel(const int* __restrict__ deg, int* __restrict__ rowp, int* __restrict__ blks) {
    __shared__ int s[256];
    int i = blockIdx.x * 256 + threadIdx.x;
    int v = (i < NN) ? deg[i] : 0;
    s[threadIdx.x] = v;
    __syncthreads();
    for (int off = 1; off < 256; off <<= 1) {
        int t = (threadIdx.x >= off) ? s[threadIdx.x - off] : 0;
        __syncthreads();
        s[threadIdx.x] += t;
        __syncthreads();
    }
    if (i < NN) rowp[i + 1] = s[threadIdx.x];
    if (threadIdx.x == 255) blks[blockIdx.x] = s[255];
}

// parallel exclusive scan of block totals (nb <= 128)
__global__ void scan2_kernel(int* __restrict__ blks, int nb) {
    __shared__ int s[128];
    int t = threadIdx.x;
    int v = (t < nb) ? blks[t] : 0;
    s[t] = v;
    __syncthreads();
    for (int off = 1; off < 128; off <<= 1) {
        int u = (t >= off) ? s[t - off] : 0;
        __syncthreads();
        s[t] += u;
        __syncthreads();
    }
    if (t < nb) blks[t] = s[t] - v;  // exclusive
}

__global__ void scan3_kernel(int* __restrict__ rowp, const int* __restrict__ blks) {
    int i = blockIdx.x * 256 + threadIdx.x;
    if (i < NN) rowp[i + 1] += blks[blockIdx.x];
    if (i == 0) rowp[0] = 0;
}

__global__ void copycur_kernel(const int* __restrict__ rowp, int* __restrict__ cur) {
    int i = blockIdx.x * 256 + threadIdx.x;
    if (i < NN) cur[i] = rowp[i];
}

__global__ void fill_kernel(const int* __restrict__ dst, int* __restrict__ cur, int* __restrict__ eid) {
    int i = blockIdx.x * blockDim.x + threadIdx.x;
    if (i < EE) {
        int pos = atomicAdd(&cur[dst[i]], 1);
        eid[pos] = i;
    }
}

// deterministic order: insertion-sort each node's edge list by edge id
__global__ void sortseg_kernel(const int* __restrict__ rowp, int* __restrict__ eid) {
    int n = blockIdx.x * 256 + threadIdx.x;
    if (n >= NN) return;
    int b = rowp[n], e = rowp[n + 1];
    for (int i = b + 1; i < e; ++i) {
        int key = eid[i];
        int j = i - 1;
        while (j >= b && eid[j] > key) { eid[j + 1] = eid[j]; --j; }
        eid[j + 1] = key;
    }
}

// gather src + edge-attr into CSR order (once per call, reused 4 layers)
__global__ void csr_gather_kernel(const int* __restrict__ csre, const int* __restrict__ srcA,
                                  const float* __restrict__ eattr,
                                  int* __restrict__ csrsrc, float4* __restrict__ ecsr) {
    int j = blockIdx.x * blockDim.x + threadIdx.x;
    if (j < EE) {
        int e = csre[j];
        csrsrc[j] = srcA[e];
        const float4* s = (const float4*)(eattr + (size_t)e * 8);
        ecsr[(size_t)j * 2] = s[0];
        ecsr[(size_t)j * 2 + 1] = s[1];
    }
}

// ---------------- per-layer: q,k,v,skip projections ----------------
// wave 0: q, wave 1: k, wave 2: v, wave 3: skip. lane-pair owns 4-channel group.
// Layouts (per node, c = 0..31 owning channels 4c..4c+3):
//   q, skip: float4 [node][32]
//   kv: uint4 [node][32] = {h2(k0,k1), h2(k2,k3), h2(v0,v1), h2(v2,v3)}
// Writer lane l (channels 2l,2l+1): c = l>>1, pair index l&1.
// block 0 also zeroes the per-layer stats region (bnpart/gmax/gsum).
__global__ __launch_bounds__(256) void qkvs_kernel(
    const float* __restrict__ hin,
    const float* __restrict__ Wq, const float* __restrict__ bq,
    const float* __restrict__ Wk, const float* __restrict__ bk,
    const float* __restrict__ Wv, const float* __restrict__ bv,
    const float* __restrict__ Ws, const float* __restrict__ bs,
    float2* __restrict__ qo,       // float4 array viewed as float2
    __half2* __restrict__ kvo,     // uint4 array viewed as __half2
    float2* __restrict__ so, float* __restrict__ lstats)
{
    if (blockIdx.x == 0) {
        for (int i = threadIdx.x; i < LSTATS_WORDS; i += 256) lstats[i] = 0.0f;
    }
    __shared__ float xs[32][32];
    int lane = threadIdx.x & 63;
    int sel = threadIdx.x >> 6;
    const float* W = (sel == 0) ? Wq : (sel == 1) ? Wk : (sel == 2) ? Wv : Ws;
    const float* bias = (sel == 0) ? bq : (sel == 1) ? bk : (sel == 2) ? bv : bs;
    float w0[32], w1[32];
#pragma unroll
    for (int f = 0; f < 32; ++f) {
        float2 t = *(const float2*)&W[f * 128 + 2 * lane];
        w0[f] = t.x; w1[f] = t.y;
    }
    float2 bvv = *(const float2*)&bias[2 * lane];

    int c = lane >> 1;
    int pr = lane & 1;
    int f2idx = c * 2 + pr;        // float2 slot within node for q/skip
    int h2k   = c * 4 + pr;        // __half2 slot for k
    int h2v   = c * 4 + 2 + pr;    // __half2 slot for v

    for (int chunk = blockIdx.x * 32; chunk < NN; chunk += gridDim.x * 32) {
        __syncthreads();
        for (int i = threadIdx.x; i < 1024; i += 256) {
            int nn = chunk + (i >> 5);
            xs[i >> 5][i & 31] = (nn < NN) ? hin[nn * 32 + (i & 31)] : 0.0f;
        }
        __syncthreads();
        int nmax = NN - chunk; if (nmax > 32) nmax = 32;
        for (int nl = 0; nl < nmax; ++nl) {
            float a0 = bvv.x, a1 = bvv.y;
#pragma unroll
            for (int f = 0; f < 32; ++f) {
                float xv = xs[nl][f];
                a0 += xv * w0[f];
                a1 += xv * w1[f];
            }
            size_t node = (size_t)(chunk + nl);
            if (sel == 0)      qo[node * 64 + f2idx] = make_float2(a0, a1);
            else if (sel == 1) kvo[node * 128 + h2k] = __float22half2_rn(make_float2(a0, a1));
            else if (sel == 2) kvo[node * 128 + h2v] = __float22half2_rn(make_float2(a0, a1));
            else               so[node * 64 + f2idx] = make_float2(a0, a1);
        }
    }
}

// ---------------- fused attention + beta gate + Wlin + ELU + BN partials ----------------
// 4 waves/block, 1 dst node per wave. Lane c=lane&31 owns channels 4c..4c+3;
// half h=lane>>5 processes edge j = jb + h (2 edges per iteration).
// Head = 8 lanes -> dot reduce is 3 shuffles; halves combined once at the end.
__global__ __launch_bounds__(256) void attn_kernel(
    const float4* __restrict__ qb4, const uint4* __restrict__ kvb4,
    const float4* __restrict__ skb4,
    const float4* __restrict__ eb4,       // ecsr (2 float4/slot)
    const int* __restrict__ srcArr,       // csrsrc[j]
    const int* __restrict__ rowp,
    const float* __restrict__ WeL, const float* __restrict__ beL,
    const float* __restrict__ WbL,
    const float* __restrict__ WlinL, const float* __restrict__ blinL,
    float* __restrict__ hlin, float* __restrict__ bnpart)
{
    __shared__ __align__(16) float shc[4 * 128];
    __shared__ float sbn[64];

    int tid = threadIdx.x;
    if (tid < 64) sbn[tid] = 0.0f;
    __syncthreads();

    int w = tid >> 6;
    int lane = tid & 63;
    int n = blockIdx.x * 4 + w;

    if (n < NN) {
        int c = lane & 31;
        int h = lane >> 5;

        // per-lane weights: We rows for channels 4c..4c+3
        float4 we[8];
#pragma unroll
        for (int d = 0; d < 8; ++d) we[d] = *(const float4*)&WeL[d * 128 + 4 * c];
        float4 be4 = *(const float4*)&beL[4 * c];
        float4 wbo = *(const float4*)&WbL[4 * c];
        float4 wbs = *(const float4*)&WbL[128 + 4 * c];
        float4 wbd = *(const float4*)&WbL[256 + 4 * c];

        float4 q4 = qb4[(size_t)n * 32 + c];
        q4.x *= RSQRT_C; q4.y *= RSQRT_C; q4.z *= RSQRT_C; q4.w *= RSQRT_C;
        float4 sk4 = skb4[(size_t)n * 32 + c];

        int beg = rowp[n], end = rowp[n + 1];
        int cnt = end - beg;
        int last = end - 1;

        float s = 0.0f, a0 = 0.0f, a1 = 0.0f, a2 = 0.0f, a3 = 0.0f;

        uint4 kvA = make_uint4(0u, 0u, 0u, 0u);
        float4 eaA0 = make_float4(0.f, 0.f, 0.f, 0.f), eaA1 = eaA0;
        int snB = 0;

        if (cnt > 0) {
            int j0 = beg + h;
            int ja = (j0 < end) ? j0 : last;
            int snA = srcArr[ja];
            kvA  = kvb4[(size_t)snA * 32 + c];
            eaA0 = eb4[(size_t)ja * 2];
            eaA1 = eb4[(size_t)ja * 2 + 1];
            int jb2 = (j0 + 2 < end) ? j0 + 2 : last;
            snB = srcArr[jb2];
        }

        for (int jb = beg; jb < end; jb += 2) {
            int j = jb + h;                        // my edge this iteration
            // prefetch next iteration (edge j+2), src for j+4
            uint4 kvN = kvb4[(size_t)snB * 32 + c];
            int jn = (j + 2 < end) ? j + 2 : last;
            float4 eaN0 = eb4[(size_t)jn * 2];
            float4 eaN1 = eb4[(size_t)jn * 2 + 1];
            int j4 = (j + 4 < end) ? j + 4 : last;
            int snC = srcArr[j4];

            // e-MLP for my 4 channels
            float ex = be4.x, ey = be4.y, ez = be4.z, ew = be4.w;
            ex += eaA0.x * we[0].x + eaA0.y * we[1].x + eaA0.z * we[2].x + eaA0.w * we[3].x
                + eaA1.x * we[4].x + eaA1.y * we[5].x + eaA1.z * we[6].x + eaA1.w * we[7].x;
            ey += eaA0.x * we[0].y + eaA0.y * we[1].y + eaA0.z * we[2].y + eaA0.w * we[3].y
                + eaA1.x * we[4].y + eaA1.y * we[5].y + eaA1.z * we[6].y + eaA1.w * we[7].y;
            ez += eaA0.x * we[0].z + eaA0.y * we[1].z + eaA0.z * we[2].z + eaA0.w * we[3].z
                + eaA1.x * we[4].z + eaA1.y * we[5].z + eaA1.z * we[6].z + eaA1.w * we[7].z;
            ew += eaA0.x * we[0].w + eaA0.y * we[1].w + eaA0.z * we[2].w + eaA0.w * we[3].w
                + eaA1.x * we[4].w + eaA1.y * we[5].w + eaA1.z * we[6].w + eaA1.w * we[7].w;

            float2 k01 = __half22float2(*(const __half2*)&kvA.x);
            float2 k23 = __half22float2(*(const __half2*)&kvA.y);
            float2 v01 = __half22float2(*(const __half2*)&kvA.z);
            float2 v23 = __half22float2(*(const __half2*)&kvA.w);

            float p = q4.x * (k01.x + ex) + q4.y * (k01.y + ey)
                    + q4.z * (k23.x + ez) + q4.w * (k23.y + ew);
            // head = 8 lanes: 3-shuffle reduce (halves independent)
            p += __shfl_xor(p, 1);
            p += __shfl_xor(p, 2);
            p += __shfl_xor(p, 4);
            float wg = (j < end) ? __expf(p) : 0.0f;
            s += wg;
            a0 = fmaf(wg, v01.x + ex, a0);
            a1 = fmaf(wg, v01.y + ey, a1);
            a2 = fmaf(wg, v23.x + ez, a2);
            a3 = fmaf(wg, v23.y + ew, a3);

            kvA = kvN; eaA0 = eaN0; eaA1 = eaN1; snB = snC;
        }

        // combine the two halves (bitwise identical both sides)
        s  += __shfl_xor(s, 32);
        a0 += __shfl_xor(a0, 32);
        a1 += __shfl_xor(a1, 32);
        a2 += __shfl_xor(a2, 32);
        a3 += __shfl_xor(a3, 32);

        float rs = (cnt > 0) ? (1.0f / s) : 0.0f;
        float o0 = a0 * rs, o1 = a1 * rs, o2 = a2 * rs, o3 = a3 * rs;

        float t = o0 * wbo.x + sk4.x * wbs.x + (o0 - sk4.x) * wbd.x
                + o1 * wbo.y + sk4.y * wbs.y + (o1 - sk4.y) * wbd.y
                + o2 * wbo.z + sk4.z * wbs.z + (o2 - sk4.z) * wbd.z
                + o3 * wbo.w + sk4.w * wbs.w + (o3 - sk4.w) * wbd.w;
#pragma unroll
        for (int off = 1; off <= 16; off <<= 1) t += __shfl_xor(t, off);
        float beta = 1.0f / (1.0f + __expf(-t));
        float4 hc4;
        hc4.x = beta * sk4.x + (1.0f - beta) * o0;
        hc4.y = beta * sk4.y + (1.0f - beta) * o1;
        hc4.z = beta * sk4.z + (1.0f - beta) * o2;
        hc4.w = beta * sk4.w + (1.0f - beta) * o3;
        if (h == 0) ((float4*)shc)[w * 32 + c] = hc4;
        // same-wave LDS RAW: no barrier needed
        int cc = lane & 31;
        int half = lane >> 5;
        float acc = 0.0f;
#pragma unroll 8
        for (int i = 0; i < 64; ++i) {
            int ch = half * 64 + i;
            acc += shc[w * 128 + ch] * WlinL[ch * 32 + cc];
        }
        acc += __shfl_xor(acc, 32);
        if (lane < 32) {
            float hv = acc + blinL[lane];
            hv = (hv > 0.0f) ? hv : expm1f(hv);
            hlin[n * 32 + lane] = hv;
            atomicAdd(&sbn[lane], hv);
            atomicAdd(&sbn[32 + lane], hv * hv);
        }
    }
    __syncthreads();
    if (tid < 64) atomicAdd(&bnpart[(blockIdx.x & (NREP - 1)) * 64 + tid], sbn[tid]);
}

// ---------------- normalize (BN finalize inline) + pooling atomics ----------------
__device__ __forceinline__ unsigned fmap_u(float x) {
    unsigned u = __float_as_uint(x);
    return (u & 0x80000000u) ? ~u : (u | 0x80000000u);
}
__device__ __forceinline__ float funmap_u(unsigned u) {
    unsigned b = (u & 0x80000000u) ? (u & 0x7fffffffu) : ~u;
    return __uint_as_float(b);
}

__global__ void norm_pool_kernel(const float* __restrict__ hl, const float* __restrict__ bnpart,
                                 const float* __restrict__ gamma, const float* __restrict__ bnbeta,
                                 const int* __restrict__ bidx, float* __restrict__ hc,
                                 unsigned* __restrict__ gmax, float* __restrict__ gsum,
                                 int doPool, int doWrite) {
    int i0 = blockIdx.x * blockDim.x + threadIdx.x;
    int stride = gridDim.x * blockDim.x;   // multiple of 32 -> c fixed per thread
    int c = i0 & 31;
    float sm = 0.0f, sq = 0.0f;
#pragma unroll
    for (int r = 0; r < NREP; ++r) { sm += bnpart[r * 64 + c]; sq += bnpart[r * 64 + 32 + c]; }
    float mean = sm * (1.0f / NN);
    float var = sq * (1.0f / NN) - mean * mean;
    float scale = gamma[c] * rsqrtf(var + 1e-5f);
    float shift = bnbeta[c] - mean * scale;
    const int tot = NN * 32;
    for (int i = i0; i < tot; i += stride) {
        int n = i >> 5;
        float val = hl[i] * scale + shift;
        if (doWrite) hc[i] = val;
        if (doPool) {
            int b = bidx[n];
            atomicMax(&gmax[b * 32 + c], fmap_u(val));
            atomicAdd(&gsum[b * 32 + c], val);
        }
    }
}

__global__ void pool_accum_kernel(const unsigned* __restrict__ gmax, const float* __restrict__ gsum,
                                  const float* __restrict__ counts, float* __restrict__ rep) {
    int i = blockIdx.x * blockDim.x + threadIdx.x;
    if (i < BB * 32) {
        int b = i >> 5, c = i & 31;
        rep[b * 64 + c] += funmap_u(gmax[i]);
        rep[b * 64 + 32 + c] += gsum[i] / counts[b];
    }
}

// ---------------- readout MLP: one block per graph ----------------
__device__ __forceinline__ float eluf(float x) { return x > 0.0f ? x : expm1f(x); }

__global__ __launch_bounds__(128) void readout_kernel(
    const float* __restrict__ rep,
    const float* __restrict__ W1, const float* __restrict__ b1,
    const float* __restrict__ W2, const float* __restrict__ b2,
    const float* __restrict__ W3, const float* __restrict__ b3,
    float* __restrict__ out)
{
    __shared__ float sr[64];
    __shared__ float sz1[128];
    __shared__ float sz2[64];
    int g = blockIdx.x;
    int t = threadIdx.x;
    if (t < 64) sr[t] = rep[g * 64 + t];
    __syncthreads();
    float acc = b1[t];
#pragma unroll 8
    for (int i = 0; i < 64; ++i) acc += sr[i] * W1[i * 128 + t];
    sz1[t] = eluf(acc);
    __syncthreads();
    if (t < 64) {
        float a2 = b2[t];
#pragma unroll 8
        for (int i = 0; i < 128; ++i) a2 += sz1[i] * W2[i * 64 + t];
        sz2[t] = eluf(a2);
    }
    __syncthreads();
    if (t < 64) {
        float p = sz2[t] * W3[t];
#pragma unroll
        for (int off = 1; off <= 32; off <<= 1) p += __shfl_xor(p, off);
        if (t == 0) out[g] = p + b3[0];
    }
}

// ---------------- host ----------------

extern "C" void kernel_launch(void* const* d_in, const int* in_sizes, int n_in,
                              void* d_out, int out_size, void* d_ws, size_t ws_size,
                              hipStream_t stream) {
    const float* x      = (const float*)d_in[0];
    const float* eattr  = (const float*)d_in[1];
    const int*   eidx   = (const int*)d_in[2];
    const int*   bidx   = (const int*)d_in[3];
    const float* Wq     = (const float*)d_in[4];
    const float* bq     = (const float*)d_in[5];
    const float* Wk     = (const float*)d_in[6];
    const float* bk     = (const float*)d_in[7];
    const float* Wv     = (const float*)d_in[8];
    const float* bv     = (const float*)d_in[9];
    const float* We     = (const float*)d_in[10];
    const float* be     = (const float*)d_in[11];
    const float* Wskip  = (const float*)d_in[12];
    const float* bskip  = (const float*)d_in[13];
    const float* Wbeta  = (const float*)d_in[14];
    const float* Wlin   = (const float*)d_in[15];
    const float* blin   = (const float*)d_in[16];
    const float* bng    = (const float*)d_in[17];
    const float* bnb    = (const float*)d_in[18];
    const float* W1     = (const float*)d_in[19];
    const float* b1     = (const float*)d_in[20];
    const float* W2     = (const float*)d_in[21];
    const float* b2     = (const float*)d_in[22];
    const float* W3     = (const float*)d_in[23];
    const float* b3     = (const float*)d_in[24];
    float* out = (float*)d_out;

    char* ws = (char*)d_ws;
    size_t off = 0;
    auto alloc = [&](size_t bytes) -> char* {
        char* p = ws + off;
        off = (off + bytes + 255) & ~(size_t)255;
        return p;
    };
    int*    rowp   = (int*)alloc((NN + 1) * 4);
    int*    deg    = (int*)alloc(NN * 4);
    int*    cur    = (int*)alloc(NN * 4);
    int*    csre   = (int*)alloc(EE * 4);
    int*    blks   = (int*)alloc(128 * 4);
    float*  counts = (float*)alloc(BB * 4 + BB * 64 * 4);   // counts + rep contiguous
    float*  rep    = counts + BB;
    float4* qB     = (float4*)alloc((size_t)NN * 32 * 16);
    uint4*  kvB    = (uint4*)alloc((size_t)NN * 32 * 16);
    float4* skB    = (float4*)alloc((size_t)NN * 32 * 16);
    float*  hlin   = (float*)alloc((size_t)NN * 32 * 4);
    float*  hcur   = (float*)alloc((size_t)NN * 32 * 4);
    float*  lstats = (float*)alloc(LSTATS_WORDS * 4);       // bnpart + gmax + gsum
    float*    bnpart = lstats;
    unsigned* gmax   = (unsigned*)(lstats + NREP * 64);
    float*    gsum   = lstats + NREP * 64 + BB * 32;

    int*    csrsrc = (int*)alloc(EE * 4);
    float4* ecsr   = (float4*)alloc((size_t)EE * 32);

    const int* srcA = eidx;
    const int* dstA = eidx + EE;

    // --- graph prep (once per call) ---
    (void)hipMemsetAsync(deg, 0, NN * 4, stream);
    (void)hipMemsetAsync(rep, 0, BB * 64 * 4, stream);

    deg_kernel<<<(EE + 255) / 256, 256, 0, stream>>>(dstA, deg);
    counts_kernel<<<1, 64, 0, stream>>>(bidx, counts);
    scan1_kernel<<<98, 256, 0, stream>>>(deg, rowp, blks);
    scan2_kernel<<<1, 128, 0, stream>>>(blks, 98);
    scan3_kernel<<<98, 256, 0, stream>>>(rowp, blks);
    copycur_kernel<<<98, 256, 0, stream>>>(rowp, cur);
    fill_kernel<<<(EE + 255) / 256, 256, 0, stream>>>(dstA, cur, csre);
    sortseg_kernel<<<98, 256, 0, stream>>>(rowp, csre);
    csr_gather_kernel<<<(EE + 255) / 256, 256, 0, stream>>>(csre, srcA, eattr, csrsrc, ecsr);

    const float* hin = x;
    for (int l = 0; l < LL; ++l) {
        qkvs_kernel<<<782, 256, 0, stream>>>(
            hin,
            Wq + l * FF * HCC, bq + l * HCC,
            Wk + l * FF * HCC, bk + l * HCC,
            Wv + l * FF * HCC, bv + l * HCC,
            Wskip + l * FF * HCC, bskip + l * HCC,
            (float2*)qB, (__half2*)kvB, (float2*)skB, lstats);

        attn_kernel<<<(NN + 3) / 4, 256, 0, stream>>>(
            qB, kvB, skB, ecsr, csrsrc, rowp,
            We + l * EDD * HCC, be + l * HCC,
            Wbeta + l * 3 * HCC,
            Wlin + l * HCC * FF, blin + l * FF,
            hlin, bnpart);

        norm_pool_kernel<<<800, 256, 0, stream>>>(hlin, bnpart, bng + l * FF, bnb + l * FF,
                                                  bidx, hcur, gmax, gsum,
                                                  (l > 0) ? 1 : 0, (l < LL - 1) ? 1 : 0);

        if (l > 0) {
            pool_accum_kernel<<<8, 256, 0, stream>>>(gmax, gsum, counts, rep);
        }
        hin = hcur;
    }

    readout_kernel<<<64, 128, 0, stream>>>(rep, W1, b1, W2, b2, W3, b3, out);
}

// Round 8
// 586.783 us; speedup vs baseline: 1.2891x; 1.2293x over previous
//
#include <hip/hip_runtime.h>
#include <hip/hip_bf16.h>
#include <hip/hip_fp16.h>
#include <math.h>

#define NN 25000
#define EE 400000
#define BB 64
#define FF 32
#define EDD 8
#define HH 4
#define CC 32
#define HCC 128
#define LL 4
#define LINN 128

#define RSQRT_C 0.17677669529663687f  // 1/sqrt(32)
#define NREP 16                        // bnpart replicas
#define LSTATS_WORDS (NREP * 64)       // bnpart only

// ---------------- CSR build ----------------

__global__ void deg_kernel(const int* __restrict__ dst, int* __restrict__ deg) {
    int i = blockIdx.x * blockDim.x + threadIdx.x;
    if (i < EE) atomicAdd(&deg[dst[i]], 1);
}

// batch_index is sorted: per-graph node offsets via binary search, zero atomics
__global__ void gstart_kernel(const int* __restrict__ bidx, int* __restrict__ gstart) {
    int b = threadIdx.x;
    if (b <= BB) {
        int lo = 0, hi = NN;
        while (lo < hi) { int mid = (lo + hi) >> 1; if (bidx[mid] < b) lo = mid + 1; else hi = mid; }
        gstart[b] = lo;
    }
}

// inclusive scan within 256-blocks; writes to rowp[i+1], block totals to blks
__global__ void scan1_kernel(const int* __restrict__ deg, int* __restrict__ rowp, int* __restrict__ blks) {
    __shared__ int s[256];
    int i = blockIdx.x * 256 + threadIdx.x;
    int v = (i < NN) ? deg[i] : 0;
    s[threadIdx.x] = v;
    __syncthreads();
    for (int off = 1; off < 256; off <<= 1) {
        int t = (threadIdx.x >= off) ? s[threadIdx.x - off] : 0;
        __syncthreads();
        s[threadIdx.x] += t;
        __syncthreads();
    }
    if (i < NN) rowp[i + 1] = s[threadIdx.x];
    if (threadIdx.x == 255) blks[blockIdx.x] = s[255];
    if (i == 0) rowp[0] = 0;
}

// parallel exclusive scan of block totals (nb <= 128)
__global__ void scan2_kernel(int* __restrict__ blks, int nb) {
    __shared__ int s[128];
    int t = threadIdx.x;
    int v = (t < nb) ? blks[t] : 0;
    s[t] = v;
    __syncthreads();
    for (int off = 1; off < 128; off <<= 1) {
        int u = (t >= off) ? s[t - off] : 0;
        __syncthreads();
        s[t] += u;
        __syncthreads();
    }
    if (t < nb) blks[t] = s[t] - v;  // exclusive
}

__global__ void scan3_kernel(int* __restrict__ rowp, const int* __restrict__ blks) {
    int i = blockIdx.x * 256 + threadIdx.x;
    if (i < NN) rowp[i + 1] += blks[blockIdx.x];
}

__global__ void fill_kernel(const int* __restrict__ dst, const int* __restrict__ rowp,
                            int* __restrict__ cnt2, int* __restrict__ eid) {
    int i = blockIdx.x * blockDim.x + threadIdx.x;
    if (i < EE) {
        int d = dst[i];
        int pos = rowp[d] + atomicAdd(&cnt2[d], 1);
        eid[pos] = i;
    }
}

// deterministic order: insertion-sort each node's edge list by edge id (scratch buffer)
__global__ void sortseg_kernel(const int* __restrict__ rowp, int* __restrict__ eid) {
    int n = blockIdx.x * 256 + threadIdx.x;
    if (n >= NN) return;
    int b = rowp[n], e = rowp[n + 1];
    int d = e - b;
    if (d <= 1) return;
    if (d <= 64) {
        int buf[64];
        for (int i = 0; i < d; ++i) buf[i] = eid[b + i];
        for (int i = 1; i < d; ++i) {
            int key = buf[i];
            int j = i - 1;
            while (j >= 0 && buf[j] > key) { buf[j + 1] = buf[j]; --j; }
            buf[j + 1] = key;
        }
        for (int i = 0; i < d; ++i) eid[b + i] = buf[i];
    } else {
        for (int i = b + 1; i < e; ++i) {
            int key = eid[i];
            int j = i - 1;
            while (j >= b && eid[j] > key) { eid[j + 1] = eid[j]; --j; }
            eid[j + 1] = key;
        }
    }
}

// gather src + edge-attr into CSR order (once per call, reused 4 layers)
__global__ void csr_gather_kernel(const int* __restrict__ csre, const int* __restrict__ srcA,
                                  const float* __restrict__ eattr,
                                  int* __restrict__ csrsrc, float4* __restrict__ ecsr) {
    int j = blockIdx.x * blockDim.x + threadIdx.x;
    if (j < EE) {
        int e = csre[j];
        csrsrc[j] = srcA[e];
        const float4* s = (const float4*)(eattr + (size_t)e * 8);
        ecsr[(size_t)j * 2] = s[0];
        ecsr[(size_t)j * 2 + 1] = s[1];
    }
}

// ---------------- per-layer: q,k,v,skip projections ----------------
// wave 0: q, wave 1: k, wave 2: v, wave 3: skip. lane-pair owns 4-channel group.
// Layouts (per node, c = 0..31 owning channels 4c..4c+3):
//   q, skip: float4 [node][32]
//   kv: uint4 [node][32] = {h2(k0,k1), h2(k2,k3), h2(v0,v1), h2(v2,v3)}
// Writer lane l (channels 2l,2l+1): c = l>>1, pair index l&1.
// block 0 also zeroes the per-layer bnpart region.
__global__ __launch_bounds__(256) void qkvs_kernel(
    const float* __restrict__ hin,
    const float* __restrict__ Wq, const float* __restrict__ bq,
    const float* __restrict__ Wk, const float* __restrict__ bk,
    const float* __restrict__ Wv, const float* __restrict__ bv,
    const float* __restrict__ Ws, const float* __restrict__ bs,
    float2* __restrict__ qo,       // float4 array viewed as float2
    __half2* __restrict__ kvo,     // uint4 array viewed as __half2
    float2* __restrict__ so, float* __restrict__ lstats)
{
    if (blockIdx.x == 0) {
        for (int i = threadIdx.x; i < LSTATS_WORDS; i += 256) lstats[i] = 0.0f;
    }
    __shared__ float xs[32][32];
    int lane = threadIdx.x & 63;
    int sel = threadIdx.x >> 6;
    const float* W = (sel == 0) ? Wq : (sel == 1) ? Wk : (sel == 2) ? Wv : Ws;
    const float* bias = (sel == 0) ? bq : (sel == 1) ? bk : (sel == 2) ? bv : bs;
    float w0[32], w1[32];
#pragma unroll
    for (int f = 0; f < 32; ++f) {
        float2 t = *(const float2*)&W[f * 128 + 2 * lane];
        w0[f] = t.x; w1[f] = t.y;
    }
    float2 bvv = *(const float2*)&bias[2 * lane];

    int c = lane >> 1;
    int pr = lane & 1;
    int f2idx = c * 2 + pr;        // float2 slot within node for q/skip
    int h2k   = c * 4 + pr;        // __half2 slot for k
    int h2v   = c * 4 + 2 + pr;    // __half2 slot for v

    for (int chunk = blockIdx.x * 32; chunk < NN; chunk += gridDim.x * 32) {
        __syncthreads();
        for (int i = threadIdx.x; i < 1024; i += 256) {
            int nn = chunk + (i >> 5);
            xs[i >> 5][i & 31] = (nn < NN) ? hin[nn * 32 + (i & 31)] : 0.0f;
        }
        __syncthreads();
        int nmax = NN - chunk; if (nmax > 32) nmax = 32;
        for (int nl = 0; nl < nmax; ++nl) {
            float a0 = bvv.x, a1 = bvv.y;
#pragma unroll
            for (int f = 0; f < 32; ++f) {
                float xv = xs[nl][f];
                a0 += xv * w0[f];
                a1 += xv * w1[f];
            }
            size_t node = (size_t)(chunk + nl);
            if (sel == 0)      qo[node * 64 + f2idx] = make_float2(a0, a1);
            else if (sel == 1) kvo[node * 128 + h2k] = __float22half2_rn(make_float2(a0, a1));
            else if (sel == 2) kvo[node * 128 + h2v] = __float22half2_rn(make_float2(a0, a1));
            else               so[node * 64 + f2idx] = make_float2(a0, a1);
        }
    }
}

// ---------------- fused attention + beta gate + Wlin + ELU + BN partials ----------------
// 4 waves/block, 1 dst node per wave. Lane c=lane&31 owns channels 4c..4c+3;
// half h=lane>>5 processes edge j = jb + h (2 edges per iteration).
// kv gather software-pipelined 2 iterations (4 edges) deep; src indices 4 iters ahead.
__global__ __launch_bounds__(256) void attn_kernel(
    const float4* __restrict__ qb4, const uint4* __restrict__ kvb4,
    const float4* __restrict__ skb4,
    const float4* __restrict__ eb4,       // ecsr (2 float4/slot)
    const int* __restrict__ srcArr,       // csrsrc[j]
    const int* __restrict__ rowp,
    const float* __restrict__ WeL, const float* __restrict__ beL,
    const float* __restrict__ WbL,
    const float* __restrict__ WlinL, const float* __restrict__ blinL,
    float* __restrict__ hlin, float* __restrict__ bnpart)
{
    __shared__ __align__(16) float shc[4 * 128];
    __shared__ float sbn[64];

    int tid = threadIdx.x;
    if (tid < 64) sbn[tid] = 0.0f;
    __syncthreads();

    int w = tid >> 6;
    int lane = tid & 63;
    int n = blockIdx.x * 4 + w;

    if (n < NN) {
        int c = lane & 31;
        int h = lane >> 5;

        // per-lane weights: We rows for channels 4c..4c+3
        float4 we[8];
#pragma unroll
        for (int d = 0; d < 8; ++d) we[d] = *(const float4*)&WeL[d * 128 + 4 * c];
        float4 be4 = *(const float4*)&beL[4 * c];
        float4 wbo = *(const float4*)&WbL[4 * c];
        float4 wbs = *(const float4*)&WbL[128 + 4 * c];
        float4 wbd = *(const float4*)&WbL[256 + 4 * c];

        float4 q4 = qb4[(size_t)n * 32 + c];
        q4.x *= RSQRT_C; q4.y *= RSQRT_C; q4.z *= RSQRT_C; q4.w *= RSQRT_C;
        float4 sk4 = skb4[(size_t)n * 32 + c];

        int beg = rowp[n], end = rowp[n + 1];
        int cnt = end - beg;
        int last = end - 1;

        float s = 0.0f, a0 = 0.0f, a1 = 0.0f, a2 = 0.0f, a3 = 0.0f;

        // pipeline state (per half): edges j, j+2 in regs; src for j+4, j+6
        uint4 kvA = make_uint4(0u, 0u, 0u, 0u), kvB = kvA;
        float4 eaA0 = make_float4(0.f, 0.f, 0.f, 0.f), eaA1 = eaA0;
        float4 eaB0 = eaA0, eaB1 = eaA0;
        int snC = 0, snD = 0;

        if (cnt > 0) {
            int j0 = beg + h;     j0 = (j0 < end) ? j0 : last;
            int j1 = beg + 2 + h; j1 = (j1 < end) ? j1 : last;
            int j2 = beg + 4 + h; j2 = (j2 < end) ? j2 : last;
            int j3 = beg + 6 + h; j3 = (j3 < end) ? j3 : last;
            int snA = srcArr[j0];
            int snB = srcArr[j1];
            snC = srcArr[j2];
            snD = srcArr[j3];
            kvA  = kvb4[(size_t)snA * 32 + c];
            kvB  = kvb4[(size_t)snB * 32 + c];
            eaA0 = eb4[(size_t)j0 * 2];
            eaA1 = eb4[(size_t)j0 * 2 + 1];
            eaB0 = eb4[(size_t)j1 * 2];
            eaB1 = eb4[(size_t)j1 * 2 + 1];
        }

        for (int jb = beg; jb < end; jb += 2) {
            int j = jb + h;                        // my edge this iteration
            // issue loads: kv for edge j+4 (2 iters ahead), ea for j+4, src for j+8
            uint4 kvC = kvb4[(size_t)snC * 32 + c];
            int jn = (j + 4 < end) ? j + 4 : last;
            float4 eaC0 = eb4[(size_t)jn * 2];
            float4 eaC1 = eb4[(size_t)jn * 2 + 1];
            int j8 = (j + 8 < end) ? j + 8 : last;
            int snE = srcArr[j8];

            // e-MLP for my 4 channels
            float ex = be4.x, ey = be4.y, ez = be4.z, ew = be4.w;
            ex += eaA0.x * we[0].x + eaA0.y * we[1].x + eaA0.z * we[2].x + eaA0.w * we[3].x
                + eaA1.x * we[4].x + eaA1.y * we[5].x + eaA1.z * we[6].x + eaA1.w * we[7].x;
            ey += eaA0.x * we[0].y + eaA0.y * we[1].y + eaA0.z * we[2].y + eaA0.w * we[3].y
                + eaA1.x * we[4].y + eaA1.y * we[5].y + eaA1.z * we[6].y + eaA1.w * we[7].y;
            ez += eaA0.x * we[0].z + eaA0.y * we[1].z + eaA0.z * we[2].z + eaA0.w * we[3].z
                + eaA1.x * we[4].z + eaA1.y * we[5].z + eaA1.z * we[6].z + eaA1.w * we[7].z;
            ew += eaA0.x * we[0].w + eaA0.y * we[1].w + eaA0.z * we[2].w + eaA0.w * we[3].w
                + eaA1.x * we[4].w + eaA1.y * we[5].w + eaA1.z * we[6].w + eaA1.w * we[7].w;

            float2 k01 = __half22float2(*(const __half2*)&kvA.x);
            float2 k23 = __half22float2(*(const __half2*)&kvA.y);
            float2 v01 = __half22float2(*(const __half2*)&kvA.z);
            float2 v23 = __half22float2(*(const __half2*)&kvA.w);

            float p = q4.x * (k01.x + ex) + q4.y * (k01.y + ey)
                    + q4.z * (k23.x + ez) + q4.w * (k23.y + ew);
            // head = 8 lanes: 3-shuffle reduce (halves independent)
            p += __shfl_xor(p, 1);
            p += __shfl_xor(p, 2);
            p += __shfl_xor(p, 4);
            float wg = (j < end) ? __expf(p) : 0.0f;
            s += wg;
            a0 = fmaf(wg, v01.x + ex, a0);
            a1 = fmaf(wg, v01.y + ey, a1);
            a2 = fmaf(wg, v23.x + ez, a2);
            a3 = fmaf(wg, v23.y + ew, a3);

            // rotate pipeline
            kvA = kvB; kvB = kvC;
            eaA0 = eaB0; eaA1 = eaB1; eaB0 = eaC0; eaB1 = eaC1;
            snC = snD; snD = snE;
        }

        // combine the two halves (bitwise identical both sides)
        s  += __shfl_xor(s, 32);
        a0 += __shfl_xor(a0, 32);
        a1 += __shfl_xor(a1, 32);
        a2 += __shfl_xor(a2, 32);
        a3 += __shfl_xor(a3, 32);

        float rs = (cnt > 0) ? (1.0f / s) : 0.0f;
        float o0 = a0 * rs, o1 = a1 * rs, o2 = a2 * rs, o3 = a3 * rs;

        float t = o0 * wbo.x + sk4.x * wbs.x + (o0 - sk4.x) * wbd.x
                + o1 * wbo.y + sk4.y * wbs.y + (o1 - sk4.y) * wbd.y
                + o2 * wbo.z + sk4.z * wbs.z + (o2 - sk4.z) * wbd.z
                + o3 * wbo.w + sk4.w * wbs.w + (o3 - sk4.w) * wbd.w;
#pragma unroll
        for (int off = 1; off <= 16; off <<= 1) t += __shfl_xor(t, off);
        float beta = 1.0f / (1.0f + __expf(-t));
        float4 hc4;
        hc4.x = beta * sk4.x + (1.0f - beta) * o0;
        hc4.y = beta * sk4.y + (1.0f - beta) * o1;
        hc4.z = beta * sk4.z + (1.0f - beta) * o2;
        hc4.w = beta * sk4.w + (1.0f - beta) * o3;
        if (h == 0) ((float4*)shc)[w * 32 + c] = hc4;
        // same-wave LDS RAW: no barrier needed
        int cc = lane & 31;
        int half = lane >> 5;
        float acc = 0.0f;
#pragma unroll 8
        for (int i = 0; i < 64; ++i) {
            int ch = half * 64 + i;
            acc += shc[w * 128 + ch] * WlinL[ch * 32 + cc];
        }
        acc += __shfl_xor(acc, 32);
        if (lane < 32) {
            float hv = acc + blinL[lane];
            hv = (hv > 0.0f) ? hv : expm1f(hv);
            hlin[n * 32 + lane] = hv;
            atomicAdd(&sbn[lane], hv);
            atomicAdd(&sbn[32 + lane], hv * hv);
        }
    }
    __syncthreads();
    if (tid < 64) atomicAdd(&bnpart[(blockIdx.x & (NREP - 1)) * 64 + tid], sbn[tid]);
}

// ---------------- BN finalize + normalize + per-graph pool (no atomics) ----------------
// one block per graph; batch_index sorted -> graph g owns nodes [gstart[g], gstart[g+1])
__global__ __launch_bounds__(256) void bnpool_kernel(
    const float* __restrict__ hlin, const float* __restrict__ bnpart,
    const float* __restrict__ gamma, const float* __restrict__ bnbeta,
    const int* __restrict__ gstart,
    float* __restrict__ hc, float* __restrict__ rep, int doPool)
{
    __shared__ float sscale[32], sshift[32];
    __shared__ float smax[8][32], ssum[8][32];
    int tid = threadIdx.x;
    int ch = tid & 31, row = tid >> 5;
    if (tid < 32) {
        float sm = 0.0f, sq = 0.0f;
#pragma unroll
        for (int r = 0; r < NREP; ++r) { sm += bnpart[r * 64 + tid]; sq += bnpart[r * 64 + 32 + tid]; }
        float mean = sm * (1.0f / NN);
        float var = sq * (1.0f / NN) - mean * mean;
        float scale = gamma[tid] * rsqrtf(var + 1e-5f);
        sscale[tid] = scale;
        sshift[tid] = bnbeta[tid] - mean * scale;
    }
    __syncthreads();
    int g = blockIdx.x;
    int gs = gstart[g], ge = gstart[g + 1];
    float scale = sscale[ch], shift = sshift[ch];
    float mx = -1e30f, sum = 0.0f;
    for (int n = gs + row; n < ge; n += 8) {
        float val = hlin[n * 32 + ch] * scale + shift;
        hc[n * 32 + ch] = val;
        mx = fmaxf(mx, val);
        sum += val;
    }
    if (doPool) {
        smax[row][ch] = mx; ssum[row][ch] = sum;
        __syncthreads();
        if (row == 0) {
#pragma unroll
            for (int r = 1; r < 8; ++r) { mx = fmaxf(mx, smax[r][ch]); sum += ssum[r][ch]; }
            int cntg = ge - gs;
            if (cntg > 0) {
                rep[g * 64 + ch]      += mx;
                rep[g * 64 + 32 + ch] += sum / (float)cntg;
            }
        }
    }
}

// ---------------- readout MLP: one block per graph ----------------
__device__ __forceinline__ float eluf(float x) { return x > 0.0f ? x : expm1f(x); }

__global__ __launch_bounds__(128) void readout_kernel(
    const float* __restrict__ rep,
    const float* __restrict__ W1, const float* __restrict__ b1,
    const float* __restrict__ W2, const float* __restrict__ b2,
    const float* __restrict__ W3, const float* __restrict__ b3,
    float* __restrict__ out)
{
    __shared__ float sr[64];
    __shared__ float sz1[128];
    __shared__ float sz2[64];
    int g = blockIdx.x;
    int t = threadIdx.x;
    if (t < 64) sr[t] = rep[g * 64 + t];
    __syncthreads();
    float acc = b1[t];
#pragma unroll 8
    for (int i = 0; i < 64; ++i) acc += sr[i] * W1[i * 128 + t];
    sz1[t] = eluf(acc);
    __syncthreads();
    if (t < 64) {
        float a2 = b2[t];
#pragma unroll 8
        for (int i = 0; i < 128; ++i) a2 += sz1[i] * W2[i * 64 + t];
        sz2[t] = eluf(a2);
    }
    __syncthreads();
    if (t < 64) {
        float p = sz2[t] * W3[t];
#pragma unroll
        for (int off = 1; off <= 32; off <<= 1) p += __shfl_xor(p, off);
        if (t == 0) out[g] = p + b3[0];
    }
}

// ---------------- host ----------------

extern "C" void kernel_launch(void* const* d_in, const int* in_sizes, int n_in,
                              void* d_out, int out_size, void* d_ws, size_t ws_size,
                              hipStream_t stream) {
    const float* x      = (const float*)d_in[0];
    const float* eattr  = (const float*)d_in[1];
    const int*   eidx   = (const int*)d_in[2];
    const int*   bidx   = (const int*)d_in[3];
    const float* Wq     = (const float*)d_in[4];
    const float* bq     = (const float*)d_in[5];
    const float* Wk     = (const float*)d_in[6];
    const float* bk     = (const float*)d_in[7];
    const float* Wv     = (const float*)d_in[8];
    const float* bv     = (const float*)d_in[9];
    const float* We     = (const float*)d_in[10];
    const float* be     = (const float*)d_in[11];
    const float* Wskip  = (const float*)d_in[12];
    const float* bskip  = (const float*)d_in[13];
    const float* Wbeta  = (const float*)d_in[14];
    const float* Wlin   = (const float*)d_in[15];
    const float* blin   = (const float*)d_in[16];
    const float* bng    = (const float*)d_in[17];
    const float* bnb    = (const float*)d_in[18];
    const float* W1     = (const float*)d_in[19];
    const float* b1     = (const float*)d_in[20];
    const float* W2     = (const float*)d_in[21];
    const float* b2     = (const float*)d_in[22];
    const float* W3     = (const float*)d_in[23];
    const float* b3     = (const float*)d_in[24];
    float* out = (float*)d_out;

    char* ws = (char*)d_ws;
    size_t off = 0;
    auto alloc = [&](size_t bytes) -> char* {
        char* p = ws + off;
        off = (off + bytes + 255) & ~(size_t)255;
        return p;
    };
    int*    rowp   = (int*)alloc((NN + 1) * 4);
    int*    degcnt = (int*)alloc(2 * NN * 4);               // deg + cnt2, one memset
    int*    deg    = degcnt;
    int*    cnt2   = degcnt + NN;
    int*    csre   = (int*)alloc(EE * 4);
    int*    blks   = (int*)alloc(128 * 4);
    int*    gstart = (int*)alloc((BB + 1) * 4);
    float*  rep    = (float*)alloc(BB * 64 * 4);
    float4* qB     = (float4*)alloc((size_t)NN * 32 * 16);
    uint4*  kvB    = (uint4*)alloc((size_t)NN * 32 * 16);
    float4* skB    = (float4*)alloc((size_t)NN * 32 * 16);
    float*  hlin   = (float*)alloc((size_t)NN * 32 * 4);
    float*  hcur   = (float*)alloc((size_t)NN * 32 * 4);
    float*  bnpart = (float*)alloc(LSTATS_WORDS * 4);
    int*    csrsrc = (int*)alloc(EE * 4);
    float4* ecsr   = (float4*)alloc((size_t)EE * 32);

    const int* srcA = eidx;
    const int* dstA = eidx + EE;

    // --- graph prep (once per call) ---
    (void)hipMemsetAsync(degcnt, 0, 2 * NN * 4, stream);
    (void)hipMemsetAsync(rep, 0, BB * 64 * 4, stream);

    deg_kernel<<<(EE + 255) / 256, 256, 0, stream>>>(dstA, deg);
    gstart_kernel<<<1, 128, 0, stream>>>(bidx, gstart);
    scan1_kernel<<<98, 256, 0, stream>>>(deg, rowp, blks);
    scan2_kernel<<<1, 128, 0, stream>>>(blks, 98);
    scan3_kernel<<<98, 256, 0, stream>>>(rowp, blks);
    fill_kernel<<<(EE + 255) / 256, 256, 0, stream>>>(dstA, rowp, cnt2, csre);
    sortseg_kernel<<<98, 256, 0, stream>>>(rowp, csre);
    csr_gather_kernel<<<(EE + 255) / 256, 256, 0, stream>>>(csre, srcA, eattr, csrsrc, ecsr);

    const float* hin = x;
    for (int l = 0; l < LL; ++l) {
        qkvs_kernel<<<782, 256, 0, stream>>>(
            hin,
            Wq + l * FF * HCC, bq + l * HCC,
            Wk + l * FF * HCC, bk + l * HCC,
            Wv + l * FF * HCC, bv + l * HCC,
            Wskip + l * FF * HCC, bskip + l * HCC,
            (float2*)qB, (__half2*)kvB, (float2*)skB, bnpart);

        attn_kernel<<<(NN + 3) / 4, 256, 0, stream>>>(
            qB, kvB, skB, ecsr, csrsrc, rowp,
            We + l * EDD * HCC, be + l * HCC,
            Wbeta + l * 3 * HCC,
            Wlin + l * HCC * FF, blin + l * FF,
            hlin, bnpart);

        bnpool_kernel<<<BB, 256, 0, stream>>>(hlin, bnpart, bng + l * FF, bnb + l * FF,
                                              gstart, hcur, rep, (l > 0) ? 1 : 0);
        hin = hcur;
    }

    readout_kernel<<<64, 128, 0, stream>>>(rep, W1, b1, W2, b2, W3, b3, out);
}